// Round 1
// baseline (634.437 us; speedup 1.0000x reference)
//
#include <hip/hip_runtime.h>
#include <hip/hip_bf16.h>
#include <math.h>

#define B_    32
#define C_    1280
#define H_    32
#define W_    32
#define N_    6890
#define HID_  256
#define MID_  128
#define HW_   (H_ * W_)

// ---------------------------------------------------------------------------
// Kernel 1: Wcomb[c][m] = sum_d reduce_w[c][d] * cls_w1[d][m]
// 1280*128 outputs, K=256. One thread per output.
// ---------------------------------------------------------------------------
__global__ __launch_bounds__(256) void k_wcomb(const float* __restrict__ rw,
                                               const float* __restrict__ w1,
                                               float* __restrict__ wcomb) {
    int o = blockIdx.x * 256 + threadIdx.x;   // < 1280*128
    int c = o >> 7;
    int m = o & 127;
    const float* rwc = rw + (size_t)c * HID_;
    float acc = 0.f;
#pragma unroll 8
    for (int d = 0; d < HID_; ++d)
        acc = fmaf(rwc[d], w1[d * MID_ + m], acc);
    wcomb[o] = acc;
}

// ---------------------------------------------------------------------------
// Kernel 2: bcomb[m] = cls_b1[m] + sum_d reduce_b[d] * cls_w1[d][m]
// ---------------------------------------------------------------------------
__global__ __launch_bounds__(128) void k_bcomb(const float* __restrict__ rb,
                                               const float* __restrict__ w1,
                                               const float* __restrict__ b1,
                                               float* __restrict__ bcomb) {
    int m = threadIdx.x;
    float acc = b1[m];
    for (int d = 0; d < HID_; ++d)
        acc = fmaf(rb[d], w1[d * MID_ + m], acc);
    bcomb[m] = acc;
}

// ---------------------------------------------------------------------------
// Kernel 3: feat_red[b][p][m] = sum_c feat[b][c][p] * Wcomb[c][m]
// Per block: one batch b, 64 pixels x 128 m. 256 threads.
// Thread (tp = t/16, tm = t%16) owns pixels p0+tp*4..+3, m = tm*8..+7
// (32 accumulators). K staged through LDS in chunks of 8.
// ---------------------------------------------------------------------------
#define KC 8
__global__ __launch_bounds__(256) void k_pregemm(const float* __restrict__ feat,
                                                 const float* __restrict__ wcomb,
                                                 float* __restrict__ fred) {
    const int b  = blockIdx.y;
    const int p0 = blockIdx.x * 64;
    const float* F = feat + (size_t)b * C_ * HW_;

    __shared__ float Ft[KC][64];
    __shared__ float Wt[KC][MID_];

    const int t  = threadIdx.x;
    const int tm = t & 15;
    const int tp = t >> 4;

    float acc[4][8];
#pragma unroll
    for (int i = 0; i < 4; ++i)
#pragma unroll
        for (int j = 0; j < 8; ++j) acc[i][j] = 0.f;

    for (int c0 = 0; c0 < C_; c0 += KC) {
        // stage F tile: KC x 64 = 512 elems, coalesced 256B rows
#pragma unroll
        for (int e = t; e < KC * 64; e += 256) {
            int kk = e >> 6, p = e & 63;
            Ft[kk][p] = F[(size_t)(c0 + kk) * HW_ + p0 + p];
        }
        // stage W tile: KC x 128 = 1024 elems, coalesced 512B rows
#pragma unroll
        for (int e = t; e < KC * MID_; e += 256) {
            int kk = e >> 7, m = e & 127;
            Wt[kk][m] = wcomb[(size_t)(c0 + kk) * MID_ + m];
        }
        __syncthreads();

#pragma unroll
        for (int kk = 0; kk < KC; ++kk) {
            float4 f  = *(const float4*)&Ft[kk][tp * 4];
            float4 wA = *(const float4*)&Wt[kk][tm * 8];
            float4 wB = *(const float4*)&Wt[kk][tm * 8 + 4];
            float fv[4] = {f.x, f.y, f.z, f.w};
            float wv[8] = {wA.x, wA.y, wA.z, wA.w, wB.x, wB.y, wB.z, wB.w};
#pragma unroll
            for (int i = 0; i < 4; ++i)
#pragma unroll
                for (int j = 0; j < 8; ++j)
                    acc[i][j] = fmaf(fv[i], wv[j], acc[i][j]);
        }
        __syncthreads();
    }

    // write fred[b][p][m], float4 stores
    float* O = fred + ((size_t)b * HW_ + p0) * MID_;
#pragma unroll
    for (int i = 0; i < 4; ++i) {
        float4 v0 = {acc[i][0], acc[i][1], acc[i][2], acc[i][3]};
        float4 v1 = {acc[i][4], acc[i][5], acc[i][6], acc[i][7]};
        *(float4*)&O[(size_t)(tp * 4 + i) * MID_ + tm * 8]     = v0;
        *(float4*)&O[(size_t)(tp * 4 + i) * MID_ + tm * 8 + 4] = v1;
    }
}

// ---------------------------------------------------------------------------
// Kernel 4: per-vertex bilinear gather (zeros padding, align_corners=True)
// + bias + relu + dot(cls_w2) + b2 + sigmoid.
// One 64-lane wave per vertex; lane handles channels 2*lane, 2*lane+1.
// ---------------------------------------------------------------------------
__global__ __launch_bounds__(256) void k_sample_head(const float* __restrict__ verts,
                                                     const float* __restrict__ fred,
                                                     const float* __restrict__ bcomb,
                                                     const float* __restrict__ w2,
                                                     const float* __restrict__ b2,
                                                     float* __restrict__ out) {
    const int wave = (blockIdx.x * 256 + threadIdx.x) >> 6;
    const int lane = threadIdx.x & 63;
    if (wave >= B_ * N_) return;
    const int b = wave / N_;
    const int n = wave - b * N_;

    const float u = verts[((size_t)b * N_ + n) * 2 + 0];
    const float v = verts[((size_t)b * N_ + n) * 2 + 1];
    const float x = (u + 1.f) * 0.5f * (float)(W_ - 1);
    const float y = (v + 1.f) * 0.5f * (float)(H_ - 1);
    const float x0f = floorf(x), y0f = floorf(y);
    const float wx = x - x0f, wy = y - y0f;
    const int x0 = (int)x0f, y0 = (int)y0f;
    const int x1 = x0 + 1,   y1 = y0 + 1;

    const float mx0 = (x0 >= 0 && x0 < W_) ? 1.f : 0.f;
    const float mx1 = (x1 >= 0 && x1 < W_) ? 1.f : 0.f;
    const float my0 = (y0 >= 0 && y0 < H_) ? 1.f : 0.f;
    const float my1 = (y1 >= 0 && y1 < H_) ? 1.f : 0.f;

    const int cx0 = min(max(x0, 0), W_ - 1), cx1 = min(max(x1, 0), W_ - 1);
    const int cy0 = min(max(y0, 0), H_ - 1), cy1 = min(max(y1, 0), H_ - 1);

    const float w00 = (1.f - wy) * (1.f - wx) * my0 * mx0;
    const float w01 = (1.f - wy) * wx         * my0 * mx1;
    const float w10 = wy         * (1.f - wx) * my1 * mx0;
    const float w11 = wy         * wx         * my1 * mx1;

    const float* Fb = fred + (size_t)b * HW_ * MID_;
    const float2 a00 = ((const float2*)&Fb[(size_t)(cy0 * W_ + cx0) * MID_])[lane];
    const float2 a01 = ((const float2*)&Fb[(size_t)(cy0 * W_ + cx1) * MID_])[lane];
    const float2 a10 = ((const float2*)&Fb[(size_t)(cy1 * W_ + cx0) * MID_])[lane];
    const float2 a11 = ((const float2*)&Fb[(size_t)(cy1 * W_ + cx1) * MID_])[lane];

    const float2 bc  = ((const float2*)bcomb)[lane];
    const float2 w2v = ((const float2*)w2)[lane];

    float hx = a00.x * w00 + a01.x * w01 + a10.x * w10 + a11.x * w11 + bc.x;
    float hy = a00.y * w00 + a01.y * w01 + a10.y * w10 + a11.y * w11 + bc.y;
    hx = fmaxf(hx, 0.f);
    hy = fmaxf(hy, 0.f);

    float s = hx * w2v.x + hy * w2v.y;
#pragma unroll
    for (int off = 32; off >= 1; off >>= 1)
        s += __shfl_xor(s, off);

    if (lane == 0) {
        const float logit = s + b2[0];
        out[wave] = 1.f / (1.f + expf(-logit));
    }
}

// ---------------------------------------------------------------------------
extern "C" void kernel_launch(void* const* d_in, const int* in_sizes, int n_in,
                              void* d_out, int out_size, void* d_ws, size_t ws_size,
                              hipStream_t stream) {
    const float* feat  = (const float*)d_in[0];
    const float* verts = (const float*)d_in[1];
    const float* rw    = (const float*)d_in[2];
    const float* rb    = (const float*)d_in[3];
    const float* w1    = (const float*)d_in[4];
    const float* b1    = (const float*)d_in[5];
    const float* w2    = (const float*)d_in[6];
    const float* b2    = (const float*)d_in[7];
    float* out = (float*)d_out;

    float* ws    = (float*)d_ws;
    float* wcomb = ws;                        // 1280*128
    float* bcomb = wcomb + (size_t)C_ * MID_; // 128
    float* fred  = bcomb + MID_;              // 32*1024*128

    k_wcomb<<<(C_ * MID_) / 256, 256, 0, stream>>>(rw, w1, wcomb);
    k_bcomb<<<1, 128, 0, stream>>>(rb, w1, b1, bcomb);

    dim3 g2(HW_ / 64, B_);
    k_pregemm<<<g2, 256, 0, stream>>>(feat, wcomb, fred);

    const int nwave = B_ * N_;                // 220480
    k_sample_head<<<(nwave + 3) / 4, 256, 0, stream>>>(verts, fred, bcomb, w2, b2, out);
}

// Round 4
// 318.576 us; speedup vs baseline: 1.9915x; 1.9915x over previous
//
#include <hip/hip_runtime.h>
#include <hip/hip_bf16.h>
#include <math.h>

#define B_    32
#define C_    1280
#define H_    32
#define W_    32
#define N_    6890
#define HID_  256
#define MID_  128
#define HW_   (H_ * W_)
#define KSTEP 32
#define KITER (C_ / KSTEP)   // 40

typedef __attribute__((ext_vector_type(8))) short short8v;
typedef __attribute__((ext_vector_type(4))) float f32x4;

// ---------------------------------------------------------------------------
// Kernel 1: Wcomb = reduce_w @ cls_w1, emitted as bf16 in MFMA-B-fragment
// linear order:
//   Bpack[((ks*8 + nb)*64 + lane)*8 + i] = Wcomb[k][n]
//   with k = ks*32 + 8*(lane>>4) + i,  n = nb*16 + (lane&15)
// Last block also computes bcomb[m] = cls_b1[m] + reduce_b @ cls_w1.
// ---------------------------------------------------------------------------
__global__ __launch_bounds__(256) void k_wcomb(
        const float* __restrict__ rw, const float* __restrict__ w1,
        const float* __restrict__ b1, const float* __restrict__ rb,
        __hip_bfloat16* __restrict__ bpack, float* __restrict__ bcomb) {
    if (blockIdx.x == (C_ * MID_) / 256) {   // extra block: bcomb
        int m = threadIdx.x;
        if (m < MID_) {
            float acc = b1[m];
            for (int d = 0; d < HID_; ++d)
                acc = fmaf(rb[d], w1[d * MID_ + m], acc);
            bcomb[m] = acc;
        }
        return;
    }
    int o = blockIdx.x * 256 + threadIdx.x;
    int c = o >> 7, m = o & 127;
    const float* rwc = rw + (size_t)c * HID_;
    float acc = 0.f;
#pragma unroll 8
    for (int d = 0; d < HID_; ++d)
        acc = fmaf(rwc[d], w1[d * MID_ + m], acc);

    int ks = c >> 5, kr = c & 31;
    int lh = kr >> 3, ii = kr & 7;         // lane-high group, element within 8
    int nb = m >> 4, col = m & 15;
    size_t idx = ((size_t)((ks * 8 + nb) * 64 + lh * 16 + col)) * 8 + ii;
    bpack[idx] = __float2bfloat16(acc);
}

// ---------------------------------------------------------------------------
// Kernel 2: fred[b][p][n] = sum_c feat[b][c][p] * Wcomb[c][n]  via MFMA.
// Block: batch b, 64 pixels x 128 n. 4 waves; wave w owns n in [32w, 32w+32).
// A (fp32) transposed through LDS As[p][k], pad 36 (2-way banks both sides).
// B fragments loaded straight from Bpack (L2-resident), no LDS.
// ---------------------------------------------------------------------------
__global__ __launch_bounds__(256) void k_pregemm(
        const float* __restrict__ feat,
        const __hip_bfloat16* __restrict__ bpack,
        float* __restrict__ fred) {
    const int b  = blockIdx.y;
    const int p0 = blockIdx.x * 64;
    const float* F = feat + (size_t)b * C_ * HW_ + p0;

    __shared__ __align__(16) float As[64][36];

    const int t  = threadIdx.x;
    const int wv = t >> 6;
    const int l  = t & 63;

    // staging geometry: per pass, wave covers 16 k-rows x 16 pixels (x4 via float4)
    const int c_loc  = 16 * (wv & 1) + (l & 15);        // k-row within step: 0..31
    const int p_loc0 = 16 * (wv >> 1) + 4 * (l >> 4);   // pass0 pixel base: 0..31
    const int p_loc1 = p_loc0 + 32;                     // pass1 pixel base: 32..63

    // MFMA fragment geometry
    const int arow = l & 15;            // A row (pixel) within 16-block
    const int akb  = 8 * (l >> 4);      // A k-base within 32-step

    f32x4 acc[4][2];
#pragma unroll
    for (int mi = 0; mi < 4; ++mi)
#pragma unroll
        for (int nb = 0; nb < 2; ++nb) acc[mi][nb] = (f32x4)0.f;

    const short8v* Bp = (const short8v*)bpack;

    // prefetch step 0
    float4 r0 = *(const float4*)&F[(size_t)c_loc * HW_ + p_loc0];
    float4 r1 = *(const float4*)&F[(size_t)c_loc * HW_ + p_loc1];

    for (int s = 0; s < KITER; ++s) {
        __syncthreads();                    // previous step's As fully consumed
        // transpose-write staged regs: 4 pixels each, same k-column
        {
            const float* q0 = (const float*)&r0;
            const float* q1 = (const float*)&r1;
#pragma unroll
            for (int j = 0; j < 4; ++j) As[p_loc0 + j][c_loc] = q0[j];
#pragma unroll
            for (int j = 0; j < 4; ++j) As[p_loc1 + j][c_loc] = q1[j];
        }
        __syncthreads();

        // prefetch step s+1 (lands under this step's compute)
        if (s + 1 < KITER) {
            const float* Fn = F + (size_t)(s + 1) * KSTEP * HW_;
            r0 = *(const float4*)&Fn[(size_t)c_loc * HW_ + p_loc0];
            r1 = *(const float4*)&Fn[(size_t)c_loc * HW_ + p_loc1];
        }

        // B fragments: coalesced 16B/lane, L2-resident
        short8v bfr0 = Bp[(size_t)(s * 8 + wv * 2 + 0) * 64 + l];
        short8v bfr1 = Bp[(size_t)(s * 8 + wv * 2 + 1) * 64 + l];

        // A fragments: 2x ds_read_b128 + cvt per 16-pixel block
        short8v afr[4];
#pragma unroll
        for (int mi = 0; mi < 4; ++mi) {
            const float* ap = &As[16 * mi + arow][akb];
            float4 lo = *(const float4*)ap;
            float4 hi = *(const float4*)(ap + 4);
            union { short8v v; __hip_bfloat16 h[8]; } u;
            const float* lp = (const float*)&lo;
            const float* hp = (const float*)&hi;
#pragma unroll
            for (int i2 = 0; i2 < 4; ++i2) u.h[i2]     = __float2bfloat16(lp[i2]);
#pragma unroll
            for (int i2 = 0; i2 < 4; ++i2) u.h[4 + i2] = __float2bfloat16(hp[i2]);
            afr[mi] = u.v;
        }

#pragma unroll
        for (int mi = 0; mi < 4; ++mi) {
            acc[mi][0] = __builtin_amdgcn_mfma_f32_16x16x32_bf16(afr[mi], bfr0, acc[mi][0], 0, 0, 0);
            acc[mi][1] = __builtin_amdgcn_mfma_f32_16x16x32_bf16(afr[mi], bfr1, acc[mi][1], 0, 0, 0);
        }
    }

    // epilogue: D layout col = lane&15, row = (lane>>4)*4 + i
    float* Ob = fred + ((size_t)b * HW_ + p0) * MID_;
    const int rbase = 4 * (l >> 4);
    const int ncol0 = 32 * wv + (l & 15);
#pragma unroll
    for (int mi = 0; mi < 4; ++mi)
#pragma unroll
        for (int nb = 0; nb < 2; ++nb)
#pragma unroll
            for (int i = 0; i < 4; ++i) {
                int prow = 16 * mi + rbase + i;
                Ob[(size_t)prow * MID_ + ncol0 + 16 * nb] = acc[mi][nb][i];
            }
}

// ---------------------------------------------------------------------------
// Kernel 3: per-vertex bilinear gather + bias + relu + dot(cls_w2) + sigmoid.
// One 64-lane wave per vertex; lane handles channels 2*lane, 2*lane+1.
// ---------------------------------------------------------------------------
__global__ __launch_bounds__(256) void k_sample_head(const float* __restrict__ verts,
                                                     const float* __restrict__ fred,
                                                     const float* __restrict__ bcomb,
                                                     const float* __restrict__ w2,
                                                     const float* __restrict__ b2,
                                                     float* __restrict__ out) {
    const int wave = (blockIdx.x * 256 + threadIdx.x) >> 6;
    const int lane = threadIdx.x & 63;
    if (wave >= B_ * N_) return;
    const int b = wave / N_;
    const int n = wave - b * N_;

    const float u = verts[((size_t)b * N_ + n) * 2 + 0];
    const float v = verts[((size_t)b * N_ + n) * 2 + 1];
    const float x = (u + 1.f) * 0.5f * (float)(W_ - 1);
    const float y = (v + 1.f) * 0.5f * (float)(H_ - 1);
    const float x0f = floorf(x), y0f = floorf(y);
    const float wx = x - x0f, wy = y - y0f;
    const int x0 = (int)x0f, y0 = (int)y0f;
    const int x1 = x0 + 1,   y1 = y0 + 1;

    const float mx0 = (x0 >= 0 && x0 < W_) ? 1.f : 0.f;
    const float mx1 = (x1 >= 0 && x1 < W_) ? 1.f : 0.f;
    const float my0 = (y0 >= 0 && y0 < H_) ? 1.f : 0.f;
    const float my1 = (y1 >= 0 && y1 < H_) ? 1.f : 0.f;

    const int cx0 = min(max(x0, 0), W_ - 1), cx1 = min(max(x1, 0), W_ - 1);
    const int cy0 = min(max(y0, 0), H_ - 1), cy1 = min(max(y1, 0), H_ - 1);

    const float w00 = (1.f - wy) * (1.f - wx) * my0 * mx0;
    const float w01 = (1.f - wy) * wx         * my0 * mx1;
    const float w10 = wy         * (1.f - wx) * my1 * mx0;
    const float w11 = wy         * wx         * my1 * mx1;

    const float* Fb = fred + (size_t)b * HW_ * MID_;
    const float2 a00 = ((const float2*)&Fb[(size_t)(cy0 * W_ + cx0) * MID_])[lane];
    const float2 a01 = ((const float2*)&Fb[(size_t)(cy0 * W_ + cx1) * MID_])[lane];
    const float2 a10 = ((const float2*)&Fb[(size_t)(cy1 * W_ + cx0) * MID_])[lane];
    const float2 a11 = ((const float2*)&Fb[(size_t)(cy1 * W_ + cx1) * MID_])[lane];

    const float2 bc  = ((const float2*)bcomb)[lane];
    const float2 w2v = ((const float2*)w2)[lane];

    float hx = a00.x * w00 + a01.x * w01 + a10.x * w10 + a11.x * w11 + bc.x;
    float hy = a00.y * w00 + a01.y * w01 + a10.y * w10 + a11.y * w11 + bc.y;
    hx = fmaxf(hx, 0.f);
    hy = fmaxf(hy, 0.f);

    float s = hx * w2v.x + hy * w2v.y;
#pragma unroll
    for (int off = 32; off >= 1; off >>= 1)
        s += __shfl_xor(s, off);

    if (lane == 0) {
        const float logit = s + b2[0];
        out[wave] = 1.f / (1.f + expf(-logit));
    }
}

// ---------------------------------------------------------------------------
extern "C" void kernel_launch(void* const* d_in, const int* in_sizes, int n_in,
                              void* d_out, int out_size, void* d_ws, size_t ws_size,
                              hipStream_t stream) {
    const float* feat  = (const float*)d_in[0];
    const float* verts = (const float*)d_in[1];
    const float* rw    = (const float*)d_in[2];
    const float* rb    = (const float*)d_in[3];
    const float* w1    = (const float*)d_in[4];
    const float* b1    = (const float*)d_in[5];
    const float* w2    = (const float*)d_in[6];
    const float* b2    = (const float*)d_in[7];
    float* out = (float*)d_out;

    float* ws = (float*)d_ws;
    float* fred = ws;                                    // 32*1024*128 f32
    __hip_bfloat16* bpack = (__hip_bfloat16*)(fred + (size_t)B_ * HW_ * MID_); // 1280*128 bf16
    float* bcomb = (float*)(bpack + (size_t)C_ * MID_);  // 128 f32

    k_wcomb<<<(C_ * MID_) / 256 + 1, 256, 0, stream>>>(rw, w1, b1, rb, bpack, bcomb);

    dim3 g2(HW_ / 64, B_);
    k_pregemm<<<g2, 256, 0, stream>>>(feat, bpack, fred);

    const int nwave = B_ * N_;   // 220480
    k_sample_head<<<(nwave + 3) / 4, 256, 0, stream>>>(verts, fred, bcomb, w2, b2, out);
}

// Round 9
// 308.400 us; speedup vs baseline: 2.0572x; 1.0330x over previous
//
#include <hip/hip_runtime.h>
#include <hip/hip_bf16.h>
#include <math.h>

#define B_    32
#define C_    1280
#define H_    32
#define W_    32
#define N_    6890
#define HID_  256
#define MID_  128
#define HW_   (H_ * W_)
#define KSTEP 32
#define KITER (C_ / KSTEP)   // 40
#define LSTR  20             // LDS row stride in uints (16B-aligned frag starts)

typedef __attribute__((ext_vector_type(8))) short short8v;
typedef __attribute__((ext_vector_type(4))) float f32x4;

static __device__ __forceinline__ uint pkbf(float a, float b) {
    union { __hip_bfloat16 h; ushort u; } ua, ub;
    ua.h = __float2bfloat16(a);
    ub.h = __float2bfloat16(b);
    return (uint)ua.u | ((uint)ub.u << 16);
}

// ---------------------------------------------------------------------------
// Kernel 1: Wcomb = reduce_w @ cls_w1 in bf16 MFMA-B-fragment linear order:
//   Bpack[((ks*8 + nb)*64 + lane)*8 + i] = Wcomb[k][n]
//   k = ks*32 + 8*(lane>>4) + i,  n = nb*16 + (lane&15)
// Last block computes bcomb[m] = cls_b1[m] + reduce_b @ cls_w1.
// ---------------------------------------------------------------------------
__global__ __launch_bounds__(256) void k_wcomb(
        const float* __restrict__ rw, const float* __restrict__ w1,
        const float* __restrict__ b1, const float* __restrict__ rb,
        __hip_bfloat16* __restrict__ bpack, float* __restrict__ bcomb) {
    if (blockIdx.x == (C_ * MID_) / 256) {
        int m = threadIdx.x;
        if (m < MID_) {
            float acc = b1[m];
            for (int d = 0; d < HID_; ++d)
                acc = fmaf(rb[d], w1[d * MID_ + m], acc);
            bcomb[m] = acc;
        }
        return;
    }
    int o = blockIdx.x * 256 + threadIdx.x;
    int c = o >> 7, m = o & 127;
    const float* rwc = rw + (size_t)c * HID_;
    float acc = 0.f;
#pragma unroll 8
    for (int d = 0; d < HID_; ++d)
        acc = fmaf(rwc[d], w1[d * MID_ + m], acc);

    int ks = c >> 5, kr = c & 31;
    int lh = kr >> 3, ii = kr & 7;
    int nb = m >> 4, col = m & 15;
    size_t idx = ((size_t)((ks * 8 + nb) * 64 + lh * 16 + col)) * 8 + ii;
    bpack[idx] = __float2bfloat16(acc);
}

// ---------------------------------------------------------------------------
// Kernel 2: fred[b][p][n] (bf16) = sum_c feat[b][c][p] * Wcomb[c][n] via MFMA.
// Block: batch b, 64 px x 128 n; 4 waves, wave w owns n in [32w,32w+32).
// A staged bf16 pair-packed in LDS (double-buffered, XOR bank swizzle),
// 1 barrier/step; A+B register-prefetched one K-step ahead.
// ---------------------------------------------------------------------------
__global__ __launch_bounds__(256) void k_pregemm(
        const float* __restrict__ feat,
        const __hip_bfloat16* __restrict__ bpack,
        __hip_bfloat16* __restrict__ fredh) {
    const int b  = blockIdx.y;
    const int p0 = blockIdx.x * 64;
    const float* F = feat + (size_t)b * C_ * HW_ + p0;

    __shared__ uint As[2][64][LSTR];   // bf16 pairs: uint col c holds k=2c,2c+1

    const int t  = threadIdx.x;
    const int wv = t >> 6;
    const int l  = t & 63;

    // staging geometry: lanes 0..7 cover 128B contiguous pixels of one k-row
    const int pl   = l & 7;                       // pixel group
    const int ql   = l >> 3;                      // k-pair sub-index
    const int pair = (wv & 1) * 8 + ql;           // k-pair 0..15 (k=2*pair,+1)
    const int px0  = 4 * pl + 32 * (wv >> 1);     // pixel base
    // bank-spread swizzle on the pair column (write side): inject px bits 3,4
    const int wcol = pair ^ ((((px0 >> 3) & 1) << 3) | (((px0 >> 4) & 1) << 2));

    // MFMA fragment geometry
    const int arow = l & 15;                      // A row (pixel) in 16-block
    const int g    = l >> 4;                      // k-octet 0..3
    const int crd  = (4 * g) ^ (((arow >> 3) & 1) << 3);  // read col base (pre-mi)

    f32x4 acc[4][2];
#pragma unroll
    for (int mi = 0; mi < 4; ++mi)
#pragma unroll
        for (int nb = 0; nb < 2; ++nb) acc[mi][nb] = (f32x4)0.f;

    const short8v* Bp = (const short8v*)bpack;

    // prologue: prefetch step 0 (A rows 2*pair, 2*pair+1; B frags)
    float4 r0 = *(const float4*)&F[(size_t)(2 * pair + 0) * HW_ + px0];
    float4 r1 = *(const float4*)&F[(size_t)(2 * pair + 1) * HW_ + px0];
    short8v b0c = Bp[(size_t)(0 * 8 + wv * 2 + 0) * 64 + l];
    short8v b1c = Bp[(size_t)(0 * 8 + wv * 2 + 1) * 64 + l];

    for (int s = 0; s < KITER; ++s) {
        const int buf = s & 1;
        // pair-pack write: As[px][pair] = (bf16(k even), bf16(k odd))
        {
            const float* q0 = (const float*)&r0;
            const float* q1 = (const float*)&r1;
#pragma unroll
            for (int j = 0; j < 4; ++j)
                As[buf][px0 + j][wcol] = pkbf(q0[j], q1[j]);
        }
        __syncthreads();

        short8v b0n = b0c, b1n = b1c;
        if (s + 1 < KITER) {        // prefetch s+1 (in flight under compute)
            const float* Fn = F + (size_t)(s + 1) * KSTEP * HW_;
            r0 = *(const float4*)&Fn[(size_t)(2 * pair + 0) * HW_ + px0];
            r1 = *(const float4*)&Fn[(size_t)(2 * pair + 1) * HW_ + px0];
            b0n = Bp[(size_t)((s + 1) * 8 + wv * 2 + 0) * 64 + l];
            b1n = Bp[(size_t)((s + 1) * 8 + wv * 2 + 1) * 64 + l];
        }

        // A fragments: one ds_read_b128 each, already bf16
#pragma unroll
        for (int mi = 0; mi < 4; ++mi) {
            short8v afr = *(const short8v*)&As[buf][16 * mi + arow][crd ^ ((mi & 1) << 2)];
            acc[mi][0] = __builtin_amdgcn_mfma_f32_16x16x32_bf16(afr, b0c, acc[mi][0], 0, 0, 0);
            acc[mi][1] = __builtin_amdgcn_mfma_f32_16x16x32_bf16(afr, b1c, acc[mi][1], 0, 0, 0);
        }
        b0c = b0n; b1c = b1n;
    }

    // epilogue: D layout col = lane&15, row = (lane>>4)*4 + i ; store bf16
    __hip_bfloat16* Ob = fredh + ((size_t)b * HW_ + p0) * MID_;
    const int rbase = 4 * (l >> 4);
    const int ncol0 = 32 * wv + (l & 15);
#pragma unroll
    for (int mi = 0; mi < 4; ++mi)
#pragma unroll
        for (int nb = 0; nb < 2; ++nb)
#pragma unroll
            for (int i = 0; i < 4; ++i) {
                int prow = 16 * mi + rbase + i;
                Ob[(size_t)prow * MID_ + ncol0 + 16 * nb] = __float2bfloat16(acc[mi][nb][i]);
            }
}

// ---------------------------------------------------------------------------
// Kernel 3: per-vertex bilinear gather (bf16 fred) + bias + relu + dot + sigmoid.
// One wave per vertex; lane handles channels 2*lane, 2*lane+1 (one uint load
// per corner). Chunked XCD swizzle: each XCD gets 4 consecutive batches ->
// 1 MB fred slice, L2-resident.
// ---------------------------------------------------------------------------
__global__ __launch_bounds__(256) void k_sample_head(const float* __restrict__ verts,
                                                     const uint* __restrict__ fredu,
                                                     const float* __restrict__ bcomb,
                                                     const float* __restrict__ w2,
                                                     const float* __restrict__ b2,
                                                     float* __restrict__ out) {
    // bijective chunked swizzle: nblocks = 55120 = 8 * 6890
    const int bid  = (blockIdx.x & 7) * (B_ * N_ / 4 / 8) + (blockIdx.x >> 3);
    const int wave = (bid * 256 + (int)threadIdx.x) >> 6;
    const int lane = threadIdx.x & 63;
    if (wave >= B_ * N_) return;
    const int b = wave / N_;
    const int n = wave - b * N_;

    const float u = verts[((size_t)b * N_ + n) * 2 + 0];
    const float v = verts[((size_t)b * N_ + n) * 2 + 1];
    const float x = (u + 1.f) * 0.5f * (float)(W_ - 1);
    const float y = (v + 1.f) * 0.5f * (float)(H_ - 1);
    const float x0f = floorf(x), y0f = floorf(y);
    const float wx = x - x0f, wy = y - y0f;
    const int x0 = (int)x0f, y0 = (int)y0f;
    const int x1 = x0 + 1,   y1 = y0 + 1;

    const float mx0 = (x0 >= 0 && x0 < W_) ? 1.f : 0.f;
    const float mx1 = (x1 >= 0 && x1 < W_) ? 1.f : 0.f;
    const float my0 = (y0 >= 0 && y0 < H_) ? 1.f : 0.f;
    const float my1 = (y1 >= 0 && y1 < H_) ? 1.f : 0.f;

    const int cx0 = min(max(x0, 0), W_ - 1), cx1 = min(max(x1, 0), W_ - 1);
    const int cy0 = min(max(y0, 0), H_ - 1), cy1 = min(max(y1, 0), H_ - 1);

    const float w00 = (1.f - wy) * (1.f - wx) * my0 * mx0;
    const float w01 = (1.f - wy) * wx         * my0 * mx1;
    const float w10 = wy         * (1.f - wx) * my1 * mx0;
    const float w11 = wy         * wx         * my1 * mx1;

    const uint* Fb = fredu + (size_t)b * HW_ * (MID_ / 2);
    const uint u00 = Fb[(size_t)(cy0 * W_ + cx0) * (MID_ / 2) + lane];
    const uint u01 = Fb[(size_t)(cy0 * W_ + cx1) * (MID_ / 2) + lane];
    const uint u10 = Fb[(size_t)(cy1 * W_ + cx0) * (MID_ / 2) + lane];
    const uint u11 = Fb[(size_t)(cy1 * W_ + cx1) * (MID_ / 2) + lane];

    const float2 bc  = ((const float2*)bcomb)[lane];
    const float2 w2v = ((const float2*)w2)[lane];

    const float lo00 = __uint_as_float(u00 << 16), hi00 = __uint_as_float(u00 & 0xffff0000u);
    const float lo01 = __uint_as_float(u01 << 16), hi01 = __uint_as_float(u01 & 0xffff0000u);
    const float lo10 = __uint_as_float(u10 << 16), hi10 = __uint_as_float(u10 & 0xffff0000u);
    const float lo11 = __uint_as_float(u11 << 16), hi11 = __uint_as_float(u11 & 0xffff0000u);

    float hx = lo00 * w00 + lo01 * w01 + lo10 * w10 + lo11 * w11 + bc.x;
    float hy = hi00 * w00 + hi01 * w01 + hi10 * w10 + hi11 * w11 + bc.y;
    hx = fmaxf(hx, 0.f);
    hy = fmaxf(hy, 0.f);

    float s = hx * w2v.x + hy * w2v.y;
#pragma unroll
    for (int off = 32; off >= 1; off >>= 1)
        s += __shfl_xor(s, off);

    if (lane == 0) {
        const float logit = s + b2[0];
        out[wave] = 1.f / (1.f + expf(-logit));
    }
}

// ---------------------------------------------------------------------------
extern "C" void kernel_launch(void* const* d_in, const int* in_sizes, int n_in,
                              void* d_out, int out_size, void* d_ws, size_t ws_size,
                              hipStream_t stream) {
    const float* feat  = (const float*)d_in[0];
    const float* verts = (const float*)d_in[1];
    const float* rw    = (const float*)d_in[2];
    const float* rb    = (const float*)d_in[3];
    const float* w1    = (const float*)d_in[4];
    const float* b1    = (const float*)d_in[5];
    const float* w2    = (const float*)d_in[6];
    const float* b2    = (const float*)d_in[7];
    float* out = (float*)d_out;

    __hip_bfloat16* fredh = (__hip_bfloat16*)d_ws;                 // 32*1024*128 bf16
    __hip_bfloat16* bpack = fredh + (size_t)B_ * HW_ * MID_;       // 1280*128 bf16
    float*          bcomb = (float*)(bpack + (size_t)C_ * MID_);   // 128 f32

    k_wcomb<<<(C_ * MID_) / 256 + 1, 256, 0, stream>>>(rw, w1, b1, rb, bpack, bcomb);

    dim3 g2(HW_ / 64, B_);
    k_pregemm<<<g2, 256, 0, stream>>>(feat, bpack, fredh);

    const int nblk = B_ * N_ / 4;   // 55120, divisible by 8
    k_sample_head<<<nblk, 256, 0, stream>>>(verts, (const uint*)fredh, bcomb, w2, b2, out);
}